// Round 14
// baseline (79.125 us; speedup 1.0000x reference)
//
#include <hip/hip_runtime.h>

// LookupAttention: B=1,H=12,N=2048,D=64, T=8, S=256, C=8, KQ=KV=4
#define HH   12
#define NN   2048
#define DD   64
#define TT   8
#define SS   256
#define KK   4
#define NHT  (HH * TT)   // 96
#define HALF 4096        // entries per (ht, n-half) = 1024 rows * 4

// XCD-aware block swizzle for 6144-block grids (m157/m204).
__device__ __forceinline__ int xcd_swz6144(int bid) {
  return (bid & 7) * 768 + (bid >> 3);
}

// Per-task selection: sigmoid -> |logit| Batcher sort -> 11 candidates ->
// exact u64-key top-4 -> coalesced store. Verified bit-identical to the
// full 256-scan (R3..R13). s[8] are the 8 hash dot products.
__device__ __forceinline__ void select_store(
    const float* __restrict__ s, int side, int ht, int n,
    float* __restrict__ selw, unsigned* __restrict__ selidx) {
  float p[8], qn[8];
  float dv[8]; int dc[8];
  int jbase = 0;
#pragma unroll
  for (int c = 0; c < 8; ++c) {
    p[c]  = 1.0f / (1.0f + expf(-s[c]));
    qn[c] = 1.0f - p[c];
    dv[c] = fabsf(s[c]); dc[c] = c;
    jbase |= (s[c] > 0.0f) ? (1 << c) : 0;
  }
#define CASX(i,j) { bool sw_ = dv[i] > dv[j];                         \
    float tv_ = sw_ ? dv[j] : dv[i]; float uv_ = sw_ ? dv[i] : dv[j]; \
    int   ti_ = sw_ ? dc[j] : dc[i]; int   ui_ = sw_ ? dc[i] : dc[j]; \
    dv[i] = tv_; dv[j] = uv_; dc[i] = ti_; dc[j] = ui_; }
  CASX(0,1) CASX(2,3) CASX(4,5) CASX(6,7)
  CASX(0,2) CASX(1,3) CASX(4,6) CASX(5,7)
  CASX(1,2) CASX(5,6)
  CASX(0,4) CASX(1,5) CASX(2,6) CASX(3,7)
  CASX(2,4) CASX(3,5)
  CASX(1,2) CASX(3,4) CASX(5,6)
#undef CASX
  int M1 = 1 << dc[0], M2 = 1 << dc[1], M3 = 1 << dc[2], M4 = 1 << dc[3];
  int cj[11] = { jbase,
                 jbase ^ M1, jbase ^ M2, jbase ^ M3, jbase ^ M4,
                 jbase ^ (M1|M2), jbase ^ (M1|M3), jbase ^ (M1|M4),
                 jbase ^ (M2|M3), jbase ^ (M2|M4), jbase ^ (M3|M4) };
  unsigned long long K0 = 0, K1 = 0, K2 = 0, K3 = 0;
#pragma unroll
  for (int kc = 0; kc < 11; ++kc) {
    int j = cj[kc];
    float w = (j & 1) ? p[0] : qn[0];   // reference association
#pragma unroll
    for (int c = 1; c < 8; ++c) w *= ((j >> c) & 1) ? p[c] : qn[c];
    unsigned long long key =
        ((unsigned long long)__float_as_uint(w) << 32) | (unsigned)(255 - j);
    bool c0 = key > K0, c1 = key > K1, c2 = key > K2, c3 = key > K3;
    K3 = c2 ? K2 : (c3 ? key : K3);
    K2 = c1 ? K1 : (c2 ? key : K2);
    K1 = c0 ? K0 : (c1 ? key : K1);
    K0 = c0 ? key : K0;
  }
  float m0 = __uint_as_float((unsigned)(K0 >> 32));
  float m1 = __uint_as_float((unsigned)(K1 >> 32));
  float m2 = __uint_as_float((unsigned)(K2 >> 32));
  float m3 = __uint_as_float((unsigned)(K3 >> 32));
  int i0 = 255 - (int)(K0 & 255u);
  int i1 = 255 - (int)(K1 & 255u);
  int i2 = 255 - (int)(K2 & 255u);
  int i3 = 255 - (int)(K3 & 255u);
  size_t o = ((size_t)side * NHT + ht) * NN + n;
  ((float4*)selw)[o] = make_float4(m0, m1, m2, m3);
  selidx[o] = (unsigned)i0 | ((unsigned)i1 << 8) | ((unsigned)i2 << 16) | ((unsigned)i3 << 24);
}

// ---------------- Kernel 1: selection (both sides) ---------------------------
// Grid: 2 sides * 12 h * 16 tiles = 384 blocks, 256 threads (4 waves).
// Block covers 128 rows; wave covers 32 rows. lane = (t,rg): t=lane>>3,
// rg=lane&7; lane processes FOUR rows (rg, +8, +16, +24) sharing one pj
// stream: 192 ds_read_b128 / 4 tasks = 48/task (was 80 — R14).
__global__ __launch_bounds__(256) void select_topk(
    const float* __restrict__ q, const float* __restrict__ kx,
    const float* __restrict__ proj,
    float* __restrict__ selw, unsigned* __restrict__ selidx) {
  __shared__ float pj[64 * 68];   // 17.4 KB, row = c*8+t, conflict-free
  __shared__ float xr[128 * 72];  // 36.9 KB

  int b = blockIdx.x;
  int side = b / 192;
  int rem  = b - side * 192;
  int h    = rem >> 4;
  int n0   = (rem & 15) * 128;
  const float* src = side ? kx : q;

  for (int e4 = threadIdx.x; e4 < 1024; e4 += 256) {
    int e = e4 * 4;
    int t = e >> 9, c = (e >> 6) & 7, d4 = (e >> 2) & 15;
    float4 pv = ((const float4*)(proj + h * 4096))[e4];
    *(float4*)(&pj[(c * 8 + t) * 68 + d4 * 4]) = pv;
  }
  for (int e4 = threadIdx.x; e4 < 2048; e4 += 256) {
    int r = e4 >> 4, d4 = e4 & 15;
    float4 xv = ((const float4*)(src + ((size_t)h * NN + n0 + r) * DD))[d4];
    *(float4*)(&xr[r * 72 + d4 * 4]) = xv;
  }
  __syncthreads();

  int wave = threadIdx.x >> 6, lane = threadIdx.x & 63;
  int t = lane >> 3, rg = lane & 7;
  int r0 = wave * 32 + rg;

  float s0[8] = {0,0,0,0,0,0,0,0}, s1[8] = {0,0,0,0,0,0,0,0};
  float s2[8] = {0,0,0,0,0,0,0,0}, s3[8] = {0,0,0,0,0,0,0,0};
  const float* xa = &xr[(r0     ) * 72];
  const float* xb = &xr[(r0 +  8) * 72];
  const float* xc = &xr[(r0 + 16) * 72];
  const float* xd = &xr[(r0 + 24) * 72];
  for (int d0 = 0; d0 < 64; d0 += 4) {
    float4 va = *(const float4*)(xa + d0);
    float4 vb = *(const float4*)(xb + d0);
    float4 vc = *(const float4*)(xc + d0);
    float4 vd = *(const float4*)(xd + d0);
#pragma unroll
    for (int c = 0; c < 8; ++c) {
      float4 pv = *(const float4*)(&pj[(c * 8 + t) * 68 + d0]);
      s0[c] += va.x*pv.x; s0[c] += va.y*pv.y; s0[c] += va.z*pv.z; s0[c] += va.w*pv.w;
      s1[c] += vb.x*pv.x; s1[c] += vb.y*pv.y; s1[c] += vb.z*pv.z; s1[c] += vb.w*pv.w;
      s2[c] += vc.x*pv.x; s2[c] += vc.y*pv.y; s2[c] += vc.z*pv.z; s2[c] += vc.w*pv.w;
      s3[c] += vd.x*pv.x; s3[c] += vd.y*pv.y; s3[c] += vd.z*pv.z; s3[c] += vd.w*pv.w;
    }
  }

  int ht = h * TT + t;
  select_store(s0, side, ht, n0 + r0,      selw, selidx);
  select_store(s1, side, ht, n0 + r0 + 8,  selw, selidx);
  select_store(s2, side, ht, n0 + r0 + 16, selw, selidx);
  select_store(s3, side, ht, n0 + r0 + 24, selw, selidx);
}

// ---------------- Kernel 2: histogram + scan + scatter (per ht-HALF) ---------
// Grid: 192 blocks = (ht, g), 1024 threads. g = n-half. Each half is fully
// self-contained: LDS histogram over its 1024 rows -> scan -> scatter into a
// 32KB LDS ebuf -> coalesced dump to entries[ht][g]. R14: doubles the
// parallelism of the least-parallel kernel (was 96 blocks = 96/256 CUs).
__global__ __launch_bounds__(1024) void scan_scatter(
    const float* __restrict__ selw, const unsigned* __restrict__ selidx,
    const float* __restrict__ mask,
    unsigned* __restrict__ offsets, unsigned long long* __restrict__ entries) {
  __shared__ unsigned long long ebuf[HALF];  // 32 KB
  __shared__ unsigned cur[SS];
  int ht = blockIdx.x >> 1;
  int g  = blockIdx.x & 1;
  int tid = threadIdx.x;
  int nbase = g * 1024;

  if (tid < SS) cur[tid] = 0;
  __syncthreads();

  {
    unsigned ip = selidx[(size_t)ht * NN + nbase + tid];
    atomicAdd(&cur[ip & 255u], 1u);
    atomicAdd(&cur[(ip >> 8) & 255u], 1u);
    atomicAdd(&cur[(ip >> 16) & 255u], 1u);
    atomicAdd(&cur[ip >> 24], 1u);
  }
  __syncthreads();

  if (tid < 64) {  // wave 0: exclusive scan of 256 counts (4 per lane)
    int lane = tid;
    unsigned c0 = cur[lane*4], c1 = cur[lane*4+1], c2 = cur[lane*4+2], c3 = cur[lane*4+3];
    unsigned sum = c0 + c1 + c2 + c3;
    unsigned x = sum;
#pragma unroll
    for (int off = 1; off <= 32; off <<= 1) {
      unsigned y = __shfl_up(x, off);
      if (lane >= off) x += y;
    }
    unsigned excl = x - sum;
    unsigned o0 = excl, o1 = excl + c0, o2 = o1 + c1, o3 = o2 + c2;
    cur[lane*4] = o0; cur[lane*4+1] = o1; cur[lane*4+2] = o2; cur[lane*4+3] = o3;
    unsigned* ob = offsets + ((size_t)ht * 2 + g) * SS;
    ob[lane*4] = o0; ob[lane*4+1] = o1; ob[lane*4+2] = o2; ob[lane*4+3] = o3;
  }
  __syncthreads();

  {
    int n = nbase + tid;
    size_t o = (size_t)ht * NN + n;   // side 0 region
    float4 w4 = ((const float4*)selw)[o];
    unsigned ip = selidx[o];
    float m = mask[n];
    unsigned b0 = ip & 255u, b1 = (ip >> 8) & 255u, b2 = (ip >> 16) & 255u, b3 = ip >> 24;
    unsigned t0 = atomicAdd(&cur[b0], 1u);
    ebuf[t0] = ((unsigned long long)__float_as_uint(w4.x * m) << 32) | (unsigned)n;
    unsigned t1 = atomicAdd(&cur[b1], 1u);
    ebuf[t1] = ((unsigned long long)__float_as_uint(w4.y * m) << 32) | (unsigned)n;
    unsigned t2 = atomicAdd(&cur[b2], 1u);
    ebuf[t2] = ((unsigned long long)__float_as_uint(w4.z * m) << 32) | (unsigned)n;
    unsigned t3 = atomicAdd(&cur[b3], 1u);
    ebuf[t3] = ((unsigned long long)__float_as_uint(w4.w * m) << 32) | (unsigned)n;
  }
  __syncthreads();

  unsigned long long* eb = entries + ((size_t)ht * 2 + g) * HALF;
  for (int i = tid; i < HALF; i += 1024) eb[i] = ebuf[i];
}

// ---------------- Kernel 3: build tables by gathering both half-bins ---------
// Grid: 6144 blocks (XCD-swizzled). Wave = (ht, s); lane = d. No atomics.
__global__ __launch_bounds__(256) void build_tables(
    const float* __restrict__ v,
    const unsigned* __restrict__ offsets,
    const unsigned long long* __restrict__ entries,
    float* __restrict__ tables) {
  int wid = xcd_swz6144(blockIdx.x) * 4 + (threadIdx.x >> 6);
  int lane = threadIdx.x & 63;
  int ht = wid >> 8;
  int s  = wid & 255;
  int h  = ht >> 3;
  const float* vh = v + (size_t)h * NN * DD;

  float acc = 0.0f;
#pragma unroll
  for (int g = 0; g < 2; ++g) {
    const unsigned* ob = offsets + ((size_t)ht * 2 + g) * SS;
    unsigned beg = ob[s];
    unsigned end = (s == SS - 1) ? HALF : ob[s + 1];
    unsigned cnt = end - beg;
    const unsigned long long* e = entries + ((size_t)ht * 2 + g) * HALF + beg;
    unsigned i = 0;
    for (; i + 8 <= cnt; i += 8) {
      unsigned long long E0 = e[i],   E1 = e[i+1], E2 = e[i+2], E3 = e[i+3];
      unsigned long long E4 = e[i+4], E5 = e[i+5], E6 = e[i+6], E7 = e[i+7];
      float f0 = vh[(size_t)(unsigned)E0 * DD + lane];
      float f1 = vh[(size_t)(unsigned)E1 * DD + lane];
      float f2 = vh[(size_t)(unsigned)E2 * DD + lane];
      float f3 = vh[(size_t)(unsigned)E3 * DD + lane];
      float f4 = vh[(size_t)(unsigned)E4 * DD + lane];
      float f5 = vh[(size_t)(unsigned)E5 * DD + lane];
      float f6 = vh[(size_t)(unsigned)E6 * DD + lane];
      float f7 = vh[(size_t)(unsigned)E7 * DD + lane];
      acc = fmaf(__uint_as_float((unsigned)(E0 >> 32)), f0, acc);
      acc = fmaf(__uint_as_float((unsigned)(E1 >> 32)), f1, acc);
      acc = fmaf(__uint_as_float((unsigned)(E2 >> 32)), f2, acc);
      acc = fmaf(__uint_as_float((unsigned)(E3 >> 32)), f3, acc);
      acc = fmaf(__uint_as_float((unsigned)(E4 >> 32)), f4, acc);
      acc = fmaf(__uint_as_float((unsigned)(E5 >> 32)), f5, acc);
      acc = fmaf(__uint_as_float((unsigned)(E6 >> 32)), f6, acc);
      acc = fmaf(__uint_as_float((unsigned)(E7 >> 32)), f7, acc);
    }
    for (; i < cnt; ++i) {
      unsigned long long e0 = e[i];
      acc += __uint_as_float((unsigned)(e0 >> 32)) * vh[(size_t)(unsigned)e0 * DD + lane];
    }
  }
  tables[(size_t)wid * DD + lane] = acc;
}

// ---------------- Kernel 4: gather output ------------------------------------
// Grid: 6144 blocks (XCD-swizzled). Wave per (h,n); lane = d. Full ILP batch.
__global__ __launch_bounds__(256) void gather_out(
    const float* __restrict__ selw, const unsigned* __restrict__ selidx,
    const float* __restrict__ tables, float* __restrict__ out) {
  int wid = xcd_swz6144(blockIdx.x) * 4 + (threadIdx.x >> 6);
  int lane = threadIdx.x & 63;
  int h = wid >> 11;
  int n = wid & 2047;

  float4 w4[8]; unsigned ip[8];
#pragma unroll
  for (int t = 0; t < TT; ++t) {
    size_t o = ((size_t)NHT + (size_t)h * TT + t) * NN + n;   // side 1 (k)
    w4[t] = ((const float4*)selw)[o];
    ip[t] = selidx[o];
  }
  float f[32];
#pragma unroll
  for (int t = 0; t < TT; ++t) {
    const float* tb = tables + ((size_t)h * TT + t) * SS * DD;
    f[t*4+0] = tb[(ip[t] & 255u) * DD + lane];
    f[t*4+1] = tb[((ip[t] >> 8) & 255u) * DD + lane];
    f[t*4+2] = tb[((ip[t] >> 16) & 255u) * DD + lane];
    f[t*4+3] = tb[(ip[t] >> 24) * DD + lane];
  }
  float acc = 0.0f;
#pragma unroll
  for (int t = 0; t < TT; ++t) {
    acc += w4[t].x * f[t*4+0];
    acc += w4[t].y * f[t*4+1];
    acc += w4[t].z * f[t*4+2];
    acc += w4[t].w * f[t*4+3];
  }
  out[((size_t)h * NN + n) * DD + lane] = acc * 0.125f;
}

extern "C" void kernel_launch(void* const* d_in, const int* in_sizes, int n_in,
                              void* d_out, int out_size, void* d_ws, size_t ws_size,
                              hipStream_t stream) {
  const float* q    = (const float*)d_in[0];
  const float* k    = (const float*)d_in[1];
  const float* v    = (const float*)d_in[2];
  const float* mask = (const float*)d_in[3];
  const float* proj = (const float*)d_in[4];
  float* out = (float*)d_out;

  // ws: tables 6.29MB | selw 6.29MB | selidx 1.57MB | offsets 192KB |
  //     entries 6.29MB (~20.7MB; every element overwritten — no memset)
  float*    tables = (float*)d_ws;
  float*    selw   = tables + (size_t)NHT * SS * DD;
  unsigned* selidx = (unsigned*)(selw + (size_t)2 * NHT * NN * KK);
  unsigned* offsets = selidx + (size_t)2 * NHT * NN;
  unsigned long long* entries = (unsigned long long*)(offsets + (size_t)NHT * 2 * SS);

  select_topk<<<dim3(384), dim3(256), 0, stream>>>(q, k, proj, selw, selidx);
  scan_scatter<<<dim3(192), dim3(1024), 0, stream>>>(selw, selidx, mask, offsets, entries);
  build_tables<<<dim3(6144), dim3(256), 0, stream>>>(v, offsets, entries, tables);
  gather_out<<<dim3(6144), dim3(256), 0, stream>>>(selw, selidx, tables, out);
}

// Round 15
// 74.854 us; speedup vs baseline: 1.0571x; 1.0571x over previous
//
#include <hip/hip_runtime.h>

// LookupAttention: B=1,H=12,N=2048,D=64, T=8, S=256, C=8, KQ=KV=4
#define HH   12
#define NN   2048
#define DD   64
#define TT   8
#define SS   256
#define KK   4
#define NHT  (HH * TT)   // 96
#define HALF 4096        // entries per (ht, n-half) = 1024 rows * 4

// XCD-aware block swizzle for 6144-block grids (m157/m204).
__device__ __forceinline__ int xcd_swz6144(int bid) {
  return (bid & 7) * 768 + (bid >> 3);
}

// Per-task selection: sigmoid -> |logit| Batcher sort -> 11 candidates ->
// exact u64-key top-4 -> coalesced store. Verified bit-identical to the
// full 256-scan (R3..R13). s[8] are the 8 hash dot products.
__device__ __forceinline__ void select_store(
    const float* __restrict__ s, int side, int ht, int n,
    float* __restrict__ selw, unsigned* __restrict__ selidx) {
  float p[8], qn[8];
  float dv[8]; int dc[8];
  int jbase = 0;
#pragma unroll
  for (int c = 0; c < 8; ++c) {
    p[c]  = 1.0f / (1.0f + expf(-s[c]));
    qn[c] = 1.0f - p[c];
    dv[c] = fabsf(s[c]); dc[c] = c;
    jbase |= (s[c] > 0.0f) ? (1 << c) : 0;
  }
#define CASX(i,j) { bool sw_ = dv[i] > dv[j];                         \
    float tv_ = sw_ ? dv[j] : dv[i]; float uv_ = sw_ ? dv[i] : dv[j]; \
    int   ti_ = sw_ ? dc[j] : dc[i]; int   ui_ = sw_ ? dc[i] : dc[j]; \
    dv[i] = tv_; dv[j] = uv_; dc[i] = ti_; dc[j] = ui_; }
  CASX(0,1) CASX(2,3) CASX(4,5) CASX(6,7)
  CASX(0,2) CASX(1,3) CASX(4,6) CASX(5,7)
  CASX(1,2) CASX(5,6)
  CASX(0,4) CASX(1,5) CASX(2,6) CASX(3,7)
  CASX(2,4) CASX(3,5)
  CASX(1,2) CASX(3,4) CASX(5,6)
#undef CASX
  int M1 = 1 << dc[0], M2 = 1 << dc[1], M3 = 1 << dc[2], M4 = 1 << dc[3];
  int cj[11] = { jbase,
                 jbase ^ M1, jbase ^ M2, jbase ^ M3, jbase ^ M4,
                 jbase ^ (M1|M2), jbase ^ (M1|M3), jbase ^ (M1|M4),
                 jbase ^ (M2|M3), jbase ^ (M2|M4), jbase ^ (M3|M4) };
  unsigned long long K0 = 0, K1 = 0, K2 = 0, K3 = 0;
#pragma unroll
  for (int kc = 0; kc < 11; ++kc) {
    int j = cj[kc];
    float w = (j & 1) ? p[0] : qn[0];   // reference association
#pragma unroll
    for (int c = 1; c < 8; ++c) w *= ((j >> c) & 1) ? p[c] : qn[c];
    unsigned long long key =
        ((unsigned long long)__float_as_uint(w) << 32) | (unsigned)(255 - j);
    bool c0 = key > K0, c1 = key > K1, c2 = key > K2, c3 = key > K3;
    K3 = c2 ? K2 : (c3 ? key : K3);
    K2 = c1 ? K1 : (c2 ? key : K2);
    K1 = c0 ? K0 : (c1 ? key : K1);
    K0 = c0 ? key : K0;
  }
  float m0 = __uint_as_float((unsigned)(K0 >> 32));
  float m1 = __uint_as_float((unsigned)(K1 >> 32));
  float m2 = __uint_as_float((unsigned)(K2 >> 32));
  float m3 = __uint_as_float((unsigned)(K3 >> 32));
  int i0 = 255 - (int)(K0 & 255u);
  int i1 = 255 - (int)(K1 & 255u);
  int i2 = 255 - (int)(K2 & 255u);
  int i3 = 255 - (int)(K3 & 255u);
  size_t o = ((size_t)side * NHT + ht) * NN + n;
  ((float4*)selw)[o] = make_float4(m0, m1, m2, m3);
  selidx[o] = (unsigned)i0 | ((unsigned)i1 << 8) | ((unsigned)i2 << 16) | ((unsigned)i3 << 24);
}

// ---------------- Kernel 1: selection (both sides) — R13 config --------------
// Grid: 768 blocks, 256 threads (4 waves). Wave covers 16 rows; lane = (t,rg),
// 2 rows/lane (rg, rg+8). R14 lesson: select is latency-hiding bound — keep
// wave count high (3072 waves); do NOT trade waves for fewer LDS reads.
__global__ __launch_bounds__(256) void select_topk(
    const float* __restrict__ q, const float* __restrict__ kx,
    const float* __restrict__ proj,
    float* __restrict__ selw, unsigned* __restrict__ selidx) {
  __shared__ float pj[64 * 68];  // row = c*8+t, stride 68 (conflict-free)
  __shared__ float xr[64 * 72];  // row stride 72

  int b = blockIdx.x;
  int side = b / 384;
  int rem  = b - side * 384;
  int h    = rem >> 5;
  int n0   = (rem & 31) * 64;
  const float* src = side ? kx : q;

  for (int e4 = threadIdx.x; e4 < 1024; e4 += 256) {
    int e = e4 * 4;
    int t = e >> 9, c = (e >> 6) & 7, d4 = (e >> 2) & 15;
    float4 pv = ((const float4*)(proj + h * 4096))[e4];
    *(float4*)(&pj[(c * 8 + t) * 68 + d4 * 4]) = pv;
  }
  for (int e4 = threadIdx.x; e4 < 1024; e4 += 256) {
    int r = e4 >> 4, d4 = e4 & 15;
    float4 xv = ((const float4*)(src + ((size_t)h * NN + n0 + r) * DD))[d4];
    *(float4*)(&xr[r * 72 + d4 * 4]) = xv;
  }
  __syncthreads();

  int wave = threadIdx.x >> 6, lane = threadIdx.x & 63;
  int t = lane >> 3, rg = lane & 7;
  int rowa = wave * 16 + rg;
  int rowb = rowa + 8;

  float sa[8] = {0,0,0,0,0,0,0,0};
  float sb[8] = {0,0,0,0,0,0,0,0};
  const float* xa = &xr[rowa * 72];
  const float* xb = &xr[rowb * 72];
  for (int d0 = 0; d0 < 64; d0 += 4) {
    float4 xva = *(const float4*)(xa + d0);
    float4 xvb = *(const float4*)(xb + d0);
#pragma unroll
    for (int c = 0; c < 8; ++c) {
      float4 pv = *(const float4*)(&pj[(c * 8 + t) * 68 + d0]);
      sa[c] += xva.x*pv.x; sa[c] += xva.y*pv.y; sa[c] += xva.z*pv.z; sa[c] += xva.w*pv.w;
      sb[c] += xvb.x*pv.x; sb[c] += xvb.y*pv.y; sb[c] += xvb.z*pv.z; sb[c] += xvb.w*pv.w;
    }
  }

  int ht = h * TT + t;
  select_store(sa, side, ht, n0 + rowa, selw, selidx);
  select_store(sb, side, ht, n0 + rowb, selw, selidx);
}

// ---------------- Kernel 2: histogram + scan + scatter (per ht-HALF) ---------
// Grid: 192 blocks = (ht, g), 1024 threads — the ONLY change vs R13 (A/B
// isolation). Each half self-contained: LDS histogram over its 1024 rows ->
// scan -> 32KB LDS ebuf -> coalesced dump to entries[ht][g].
__global__ __launch_bounds__(1024) void scan_scatter(
    const float* __restrict__ selw, const unsigned* __restrict__ selidx,
    const float* __restrict__ mask,
    unsigned* __restrict__ offsets, unsigned long long* __restrict__ entries) {
  __shared__ unsigned long long ebuf[HALF];  // 32 KB
  __shared__ unsigned cur[SS];
  int ht = blockIdx.x >> 1;
  int g  = blockIdx.x & 1;
  int tid = threadIdx.x;
  int nbase = g * 1024;

  if (tid < SS) cur[tid] = 0;
  __syncthreads();

  {
    unsigned ip = selidx[(size_t)ht * NN + nbase + tid];
    atomicAdd(&cur[ip & 255u], 1u);
    atomicAdd(&cur[(ip >> 8) & 255u], 1u);
    atomicAdd(&cur[(ip >> 16) & 255u], 1u);
    atomicAdd(&cur[ip >> 24], 1u);
  }
  __syncthreads();

  if (tid < 64) {  // wave 0: exclusive scan of 256 counts (4 per lane)
    int lane = tid;
    unsigned c0 = cur[lane*4], c1 = cur[lane*4+1], c2 = cur[lane*4+2], c3 = cur[lane*4+3];
    unsigned sum = c0 + c1 + c2 + c3;
    unsigned x = sum;
#pragma unroll
    for (int off = 1; off <= 32; off <<= 1) {
      unsigned y = __shfl_up(x, off);
      if (lane >= off) x += y;
    }
    unsigned excl = x - sum;
    unsigned o0 = excl, o1 = excl + c0, o2 = o1 + c1, o3 = o2 + c2;
    cur[lane*4] = o0; cur[lane*4+1] = o1; cur[lane*4+2] = o2; cur[lane*4+3] = o3;
    unsigned* ob = offsets + ((size_t)ht * 2 + g) * SS;
    ob[lane*4] = o0; ob[lane*4+1] = o1; ob[lane*4+2] = o2; ob[lane*4+3] = o3;
  }
  __syncthreads();

  {
    int n = nbase + tid;
    size_t o = (size_t)ht * NN + n;   // side 0 region
    float4 w4 = ((const float4*)selw)[o];
    unsigned ip = selidx[o];
    float m = mask[n];
    unsigned b0 = ip & 255u, b1 = (ip >> 8) & 255u, b2 = (ip >> 16) & 255u, b3 = ip >> 24;
    unsigned t0 = atomicAdd(&cur[b0], 1u);
    ebuf[t0] = ((unsigned long long)__float_as_uint(w4.x * m) << 32) | (unsigned)n;
    unsigned t1 = atomicAdd(&cur[b1], 1u);
    ebuf[t1] = ((unsigned long long)__float_as_uint(w4.y * m) << 32) | (unsigned)n;
    unsigned t2 = atomicAdd(&cur[b2], 1u);
    ebuf[t2] = ((unsigned long long)__float_as_uint(w4.z * m) << 32) | (unsigned)n;
    unsigned t3 = atomicAdd(&cur[b3], 1u);
    ebuf[t3] = ((unsigned long long)__float_as_uint(w4.w * m) << 32) | (unsigned)n;
  }
  __syncthreads();

  unsigned long long* eb = entries + ((size_t)ht * 2 + g) * HALF;
  for (int i = tid; i < HALF; i += 1024) eb[i] = ebuf[i];
}

// ---------------- Kernel 3: build tables by gathering both half-bins ---------
// Grid: 6144 blocks (XCD-swizzled). Wave = (ht, s); lane = d. No atomics.
__global__ __launch_bounds__(256) void build_tables(
    const float* __restrict__ v,
    const unsigned* __restrict__ offsets,
    const unsigned long long* __restrict__ entries,
    float* __restrict__ tables) {
  int wid = xcd_swz6144(blockIdx.x) * 4 + (threadIdx.x >> 6);
  int lane = threadIdx.x & 63;
  int ht = wid >> 8;
  int s  = wid & 255;
  int h  = ht >> 3;
  const float* vh = v + (size_t)h * NN * DD;

  float acc = 0.0f;
#pragma unroll
  for (int g = 0; g < 2; ++g) {
    const unsigned* ob = offsets + ((size_t)ht * 2 + g) * SS;
    unsigned beg = ob[s];
    unsigned end = (s == SS - 1) ? HALF : ob[s + 1];
    unsigned cnt = end - beg;
    const unsigned long long* e = entries + ((size_t)ht * 2 + g) * HALF + beg;
    unsigned i = 0;
    for (; i + 8 <= cnt; i += 8) {
      unsigned long long E0 = e[i],   E1 = e[i+1], E2 = e[i+2], E3 = e[i+3];
      unsigned long long E4 = e[i+4], E5 = e[i+5], E6 = e[i+6], E7 = e[i+7];
      float f0 = vh[(size_t)(unsigned)E0 * DD + lane];
      float f1 = vh[(size_t)(unsigned)E1 * DD + lane];
      float f2 = vh[(size_t)(unsigned)E2 * DD + lane];
      float f3 = vh[(size_t)(unsigned)E3 * DD + lane];
      float f4 = vh[(size_t)(unsigned)E4 * DD + lane];
      float f5 = vh[(size_t)(unsigned)E5 * DD + lane];
      float f6 = vh[(size_t)(unsigned)E6 * DD + lane];
      float f7 = vh[(size_t)(unsigned)E7 * DD + lane];
      acc = fmaf(__uint_as_float((unsigned)(E0 >> 32)), f0, acc);
      acc = fmaf(__uint_as_float((unsigned)(E1 >> 32)), f1, acc);
      acc = fmaf(__uint_as_float((unsigned)(E2 >> 32)), f2, acc);
      acc = fmaf(__uint_as_float((unsigned)(E3 >> 32)), f3, acc);
      acc = fmaf(__uint_as_float((unsigned)(E4 >> 32)), f4, acc);
      acc = fmaf(__uint_as_float((unsigned)(E5 >> 32)), f5, acc);
      acc = fmaf(__uint_as_float((unsigned)(E6 >> 32)), f6, acc);
      acc = fmaf(__uint_as_float((unsigned)(E7 >> 32)), f7, acc);
    }
    for (; i < cnt; ++i) {
      unsigned long long e0 = e[i];
      acc += __uint_as_float((unsigned)(e0 >> 32)) * vh[(size_t)(unsigned)e0 * DD + lane];
    }
  }
  tables[(size_t)wid * DD + lane] = acc;
}

// ---------------- Kernel 4: gather output — R13 config -----------------------
// Grid: 6144 blocks (XCD-swizzled). Wave per (h,n); lane = d. Full ILP batch.
__global__ __launch_bounds__(256) void gather_out(
    const float* __restrict__ selw, const unsigned* __restrict__ selidx,
    const float* __restrict__ tables, float* __restrict__ out) {
  int wid = xcd_swz6144(blockIdx.x) * 4 + (threadIdx.x >> 6);
  int lane = threadIdx.x & 63;
  int h = wid >> 11;
  int n = wid & 2047;

  float4 w4[8]; unsigned ip[8];
#pragma unroll
  for (int t = 0; t < TT; ++t) {
    size_t o = ((size_t)NHT + (size_t)h * TT + t) * NN + n;   // side 1 (k)
    w4[t] = ((const float4*)selw)[o];
    ip[t] = selidx[o];
  }
  float f[32];
#pragma unroll
  for (int t = 0; t < TT; ++t) {
    const float* tb = tables + ((size_t)h * TT + t) * SS * DD;
    f[t*4+0] = tb[(ip[t] & 255u) * DD + lane];
    f[t*4+1] = tb[((ip[t] >> 8) & 255u) * DD + lane];
    f[t*4+2] = tb[((ip[t] >> 16) & 255u) * DD + lane];
    f[t*4+3] = tb[(ip[t] >> 24) * DD + lane];
  }
  float acc = 0.0f;
#pragma unroll
  for (int t = 0; t < TT; ++t) {
    acc += w4[t].x * f[t*4+0];
    acc += w4[t].y * f[t*4+1];
    acc += w4[t].z * f[t*4+2];
    acc += w4[t].w * f[t*4+3];
  }
  out[((size_t)h * NN + n) * DD + lane] = acc * 0.125f;
}

extern "C" void kernel_launch(void* const* d_in, const int* in_sizes, int n_in,
                              void* d_out, int out_size, void* d_ws, size_t ws_size,
                              hipStream_t stream) {
  const float* q    = (const float*)d_in[0];
  const float* k    = (const float*)d_in[1];
  const float* v    = (const float*)d_in[2];
  const float* mask = (const float*)d_in[3];
  const float* proj = (const float*)d_in[4];
  float* out = (float*)d_out;

  // ws: tables 6.29MB | selw 6.29MB | selidx 1.57MB | offsets 192KB |
  //     entries 6.29MB (~20.7MB; every element overwritten — no memset)
  float*    tables = (float*)d_ws;
  float*    selw   = tables + (size_t)NHT * SS * DD;
  unsigned* selidx = (unsigned*)(selw + (size_t)2 * NHT * NN * KK);
  unsigned* offsets = selidx + (size_t)2 * NHT * NN;
  unsigned long long* entries = (unsigned long long*)(offsets + (size_t)NHT * 2 * SS);

  select_topk<<<dim3(768), dim3(256), 0, stream>>>(q, k, proj, selw, selidx);
  scan_scatter<<<dim3(192), dim3(1024), 0, stream>>>(selw, selidx, mask, offsets, entries);
  build_tables<<<dim3(6144), dim3(256), 0, stream>>>(v, offsets, entries, tables);
  gather_out<<<dim3(6144), dim3(256), 0, stream>>>(selw, selidx, tables, out);
}

// Round 16
// 71.643 us; speedup vs baseline: 1.1044x; 1.0448x over previous
//
#include <hip/hip_runtime.h>

// LookupAttention: B=1,H=12,N=2048,D=64, T=8, S=256, C=8, KQ=KV=4
// FINAL (R13 config — session best 71.7us): 4-kernel pipeline:
//   select_topk  (768 blocks): exact candidate-pruned top-4 per (side,h,n,t)
//   scan_scatter  (96 blocks): LDS histogram+scan+bin-scatter, coalesced dump
//   build_tables (6144 blks) : bin-gather, no atomics, 8-deep ILP, XCD swizzle
//   gather_out   (6144 blks) : table-row gather, full ILP batch, XCD swizzle
#define HH   12
#define NN   2048
#define DD   64
#define TT   8
#define SS   256
#define KK   4
#define NHT  (HH * TT)   // 96

// XCD-aware block swizzle for 6144-block grids (m157/m204).
__device__ __forceinline__ int xcd_swz6144(int bid) {
  return (bid & 7) * 768 + (bid >> 3);
}

// Per-task selection: sigmoid -> |logit| Batcher sort -> 11 candidates ->
// exact u64-key top-4 -> coalesced store. Verified bit-identical to the
// full 256-scan (R3..R13). s[8] are the 8 hash dot products.
__device__ __forceinline__ void select_store(
    const float* __restrict__ s, int side, int ht, int n,
    float* __restrict__ selw, unsigned* __restrict__ selidx) {
  float p[8], qn[8];
  float dv[8]; int dc[8];
  int jbase = 0;
#pragma unroll
  for (int c = 0; c < 8; ++c) {
    p[c]  = 1.0f / (1.0f + expf(-s[c]));
    qn[c] = 1.0f - p[c];
    dv[c] = fabsf(s[c]); dc[c] = c;
    jbase |= (s[c] > 0.0f) ? (1 << c) : 0;
  }
#define CASX(i,j) { bool sw_ = dv[i] > dv[j];                         \
    float tv_ = sw_ ? dv[j] : dv[i]; float uv_ = sw_ ? dv[i] : dv[j]; \
    int   ti_ = sw_ ? dc[j] : dc[i]; int   ui_ = sw_ ? dc[i] : dc[j]; \
    dv[i] = tv_; dv[j] = uv_; dc[i] = ti_; dc[j] = ui_; }
  CASX(0,1) CASX(2,3) CASX(4,5) CASX(6,7)
  CASX(0,2) CASX(1,3) CASX(4,6) CASX(5,7)
  CASX(1,2) CASX(5,6)
  CASX(0,4) CASX(1,5) CASX(2,6) CASX(3,7)
  CASX(2,4) CASX(3,5)
  CASX(1,2) CASX(3,4) CASX(5,6)
#undef CASX
  int M1 = 1 << dc[0], M2 = 1 << dc[1], M3 = 1 << dc[2], M4 = 1 << dc[3];
  int cj[11] = { jbase,
                 jbase ^ M1, jbase ^ M2, jbase ^ M3, jbase ^ M4,
                 jbase ^ (M1|M2), jbase ^ (M1|M3), jbase ^ (M1|M4),
                 jbase ^ (M2|M3), jbase ^ (M2|M4), jbase ^ (M3|M4) };
  unsigned long long K0 = 0, K1 = 0, K2 = 0, K3 = 0;
#pragma unroll
  for (int kc = 0; kc < 11; ++kc) {
    int j = cj[kc];
    float w = (j & 1) ? p[0] : qn[0];   // reference association
#pragma unroll
    for (int c = 1; c < 8; ++c) w *= ((j >> c) & 1) ? p[c] : qn[c];
    unsigned long long key =
        ((unsigned long long)__float_as_uint(w) << 32) | (unsigned)(255 - j);
    bool c0 = key > K0, c1 = key > K1, c2 = key > K2, c3 = key > K3;
    K3 = c2 ? K2 : (c3 ? key : K3);
    K2 = c1 ? K1 : (c2 ? key : K2);
    K1 = c0 ? K0 : (c1 ? key : K1);
    K0 = c0 ? key : K0;
  }
  float m0 = __uint_as_float((unsigned)(K0 >> 32));
  float m1 = __uint_as_float((unsigned)(K1 >> 32));
  float m2 = __uint_as_float((unsigned)(K2 >> 32));
  float m3 = __uint_as_float((unsigned)(K3 >> 32));
  int i0 = 255 - (int)(K0 & 255u);
  int i1 = 255 - (int)(K1 & 255u);
  int i2 = 255 - (int)(K2 & 255u);
  int i3 = 255 - (int)(K3 & 255u);
  size_t o = ((size_t)side * NHT + ht) * NN + n;
  ((float4*)selw)[o] = make_float4(m0, m1, m2, m3);
  selidx[o] = (unsigned)i0 | ((unsigned)i1 << 8) | ((unsigned)i2 << 16) | ((unsigned)i3 << 24);
}

// ---------------- Kernel 1: selection (both sides) ---------------------------
// Grid: 768 blocks, 256 threads (4 waves). Wave covers 16 rows; lane = (t,rg),
// 2 rows/lane (rg, rg+8) sharing one pj stream. Keep wave count high (3072):
// select is latency-hiding bound (R14 lesson), coalesced 128B stores (R7 fix).
__global__ __launch_bounds__(256) void select_topk(
    const float* __restrict__ q, const float* __restrict__ kx,
    const float* __restrict__ proj,
    float* __restrict__ selw, unsigned* __restrict__ selidx) {
  __shared__ float pj[64 * 68];  // row = c*8+t, stride 68 (conflict-free)
  __shared__ float xr[64 * 72];  // row stride 72

  int b = blockIdx.x;
  int side = b / 384;
  int rem  = b - side * 384;
  int h    = rem >> 5;
  int n0   = (rem & 31) * 64;
  const float* src = side ? kx : q;

  for (int e4 = threadIdx.x; e4 < 1024; e4 += 256) {
    int e = e4 * 4;
    int t = e >> 9, c = (e >> 6) & 7, d4 = (e >> 2) & 15;
    float4 pv = ((const float4*)(proj + h * 4096))[e4];
    *(float4*)(&pj[(c * 8 + t) * 68 + d4 * 4]) = pv;
  }
  for (int e4 = threadIdx.x; e4 < 1024; e4 += 256) {
    int r = e4 >> 4, d4 = e4 & 15;
    float4 xv = ((const float4*)(src + ((size_t)h * NN + n0 + r) * DD))[d4];
    *(float4*)(&xr[r * 72 + d4 * 4]) = xv;
  }
  __syncthreads();

  int wave = threadIdx.x >> 6, lane = threadIdx.x & 63;
  int t = lane >> 3, rg = lane & 7;
  int rowa = wave * 16 + rg;
  int rowb = rowa + 8;

  float sa[8] = {0,0,0,0,0,0,0,0};
  float sb[8] = {0,0,0,0,0,0,0,0};
  const float* xa = &xr[rowa * 72];
  const float* xb = &xr[rowb * 72];
  for (int d0 = 0; d0 < 64; d0 += 4) {
    float4 xva = *(const float4*)(xa + d0);
    float4 xvb = *(const float4*)(xb + d0);
#pragma unroll
    for (int c = 0; c < 8; ++c) {
      float4 pv = *(const float4*)(&pj[(c * 8 + t) * 68 + d0]);
      sa[c] += xva.x*pv.x; sa[c] += xva.y*pv.y; sa[c] += xva.z*pv.z; sa[c] += xva.w*pv.w;
      sb[c] += xvb.x*pv.x; sb[c] += xvb.y*pv.y; sb[c] += xvb.z*pv.z; sb[c] += xvb.w*pv.w;
    }
  }

  int ht = h * TT + t;
  select_store(sa, side, ht, n0 + rowa, selw, selidx);
  select_store(sb, side, ht, n0 + rowb, selw, selidx);
}

// ---------------- Kernel 2: histogram + scan + scatter into bins -------------
// Grid: 96 blocks, 1024 threads. Self-contained per (h,t): LDS histogram ->
// wave-0 scan -> scatter into LDS ebuf (64KB) -> coalesced 64KB dump.
// Entry = u64 { hi: bits(w*mask), lo: n }. (R15 A/B: 192-block half-split
// regressed — monolithic per-ht is faster.)
__global__ __launch_bounds__(1024) void scan_scatter(
    const float* __restrict__ selw, const unsigned* __restrict__ selidx,
    const float* __restrict__ mask,
    unsigned* __restrict__ offsets, unsigned long long* __restrict__ entries) {
  __shared__ unsigned long long ebuf[NN * KK];  // 64 KB
  __shared__ unsigned cur[SS];
  int ht = blockIdx.x;
  int tid = threadIdx.x;

  if (tid < SS) cur[tid] = 0;
  __syncthreads();

  for (int n = tid; n < NN; n += 1024) {
    unsigned ip = selidx[(size_t)ht * NN + n];
    atomicAdd(&cur[ip & 255u], 1u);
    atomicAdd(&cur[(ip >> 8) & 255u], 1u);
    atomicAdd(&cur[(ip >> 16) & 255u], 1u);
    atomicAdd(&cur[ip >> 24], 1u);
  }
  __syncthreads();

  if (tid < 64) {  // wave 0: exclusive scan of 256 counts (4 per lane)
    int lane = tid;
    unsigned c0 = cur[lane*4], c1 = cur[lane*4+1], c2 = cur[lane*4+2], c3 = cur[lane*4+3];
    unsigned sum = c0 + c1 + c2 + c3;
    unsigned x = sum;
#pragma unroll
    for (int off = 1; off <= 32; off <<= 1) {
      unsigned y = __shfl_up(x, off);
      if (lane >= off) x += y;
    }
    unsigned excl = x - sum;
    unsigned o0 = excl, o1 = excl + c0, o2 = o1 + c1, o3 = o2 + c2;
    cur[lane*4] = o0; cur[lane*4+1] = o1; cur[lane*4+2] = o2; cur[lane*4+3] = o3;
    unsigned* ob = offsets + (size_t)ht * SS;
    ob[lane*4] = o0; ob[lane*4+1] = o1; ob[lane*4+2] = o2; ob[lane*4+3] = o3;
  }
  __syncthreads();

  for (int n = tid; n < NN; n += 1024) {
    size_t o = (size_t)ht * NN + n;   // side 0 region
    float4 w4 = ((const float4*)selw)[o];
    unsigned ip = selidx[o];
    float m = mask[n];
    unsigned b0 = ip & 255u, b1 = (ip >> 8) & 255u, b2 = (ip >> 16) & 255u, b3 = ip >> 24;
    unsigned s0 = atomicAdd(&cur[b0], 1u);
    ebuf[s0] = ((unsigned long long)__float_as_uint(w4.x * m) << 32) | (unsigned)n;
    unsigned s1 = atomicAdd(&cur[b1], 1u);
    ebuf[s1] = ((unsigned long long)__float_as_uint(w4.y * m) << 32) | (unsigned)n;
    unsigned s2 = atomicAdd(&cur[b2], 1u);
    ebuf[s2] = ((unsigned long long)__float_as_uint(w4.z * m) << 32) | (unsigned)n;
    unsigned s3 = atomicAdd(&cur[b3], 1u);
    ebuf[s3] = ((unsigned long long)__float_as_uint(w4.w * m) << 32) | (unsigned)n;
  }
  __syncthreads();

  unsigned long long* eb = entries + (size_t)ht * (NN * KK);
  for (int i = tid; i < NN * KK; i += 1024) eb[i] = ebuf[i];
}

// ---------------- Kernel 3: build tables by gathering bins -------------------
// Grid: 6144 blocks (XCD-swizzled). Wave = (ht, s); lane = d. No atomics.
// cnt derived from offsets; 8-deep two-phase loads for ILP.
__global__ __launch_bounds__(256) void build_tables(
    const float* __restrict__ v,
    const unsigned* __restrict__ offsets,
    const unsigned long long* __restrict__ entries,
    float* __restrict__ tables) {
  int wid = xcd_swz6144(blockIdx.x) * 4 + (threadIdx.x >> 6);
  int lane = threadIdx.x & 63;
  int ht = wid >> 8;
  int s  = wid & 255;
  int h  = ht >> 3;

  unsigned beg = offsets[(size_t)ht * SS + s];
  unsigned end = (s == SS - 1) ? (NN * KK) : offsets[(size_t)ht * SS + s + 1];
  unsigned cnt = end - beg;
  const unsigned long long* e = entries + (size_t)ht * (NN * KK) + beg;
  const float* vh = v + (size_t)h * NN * DD;

  float acc = 0.0f;
  unsigned i = 0;
  for (; i + 8 <= cnt; i += 8) {
    unsigned long long E0 = e[i],   E1 = e[i+1], E2 = e[i+2], E3 = e[i+3];
    unsigned long long E4 = e[i+4], E5 = e[i+5], E6 = e[i+6], E7 = e[i+7];
    float f0 = vh[(size_t)(unsigned)E0 * DD + lane];
    float f1 = vh[(size_t)(unsigned)E1 * DD + lane];
    float f2 = vh[(size_t)(unsigned)E2 * DD + lane];
    float f3 = vh[(size_t)(unsigned)E3 * DD + lane];
    float f4 = vh[(size_t)(unsigned)E4 * DD + lane];
    float f5 = vh[(size_t)(unsigned)E5 * DD + lane];
    float f6 = vh[(size_t)(unsigned)E6 * DD + lane];
    float f7 = vh[(size_t)(unsigned)E7 * DD + lane];
    acc = fmaf(__uint_as_float((unsigned)(E0 >> 32)), f0, acc);
    acc = fmaf(__uint_as_float((unsigned)(E1 >> 32)), f1, acc);
    acc = fmaf(__uint_as_float((unsigned)(E2 >> 32)), f2, acc);
    acc = fmaf(__uint_as_float((unsigned)(E3 >> 32)), f3, acc);
    acc = fmaf(__uint_as_float((unsigned)(E4 >> 32)), f4, acc);
    acc = fmaf(__uint_as_float((unsigned)(E5 >> 32)), f5, acc);
    acc = fmaf(__uint_as_float((unsigned)(E6 >> 32)), f6, acc);
    acc = fmaf(__uint_as_float((unsigned)(E7 >> 32)), f7, acc);
  }
  for (; i < cnt; ++i) {
    unsigned long long e0 = e[i];
    acc += __uint_as_float((unsigned)(e0 >> 32)) * vh[(size_t)(unsigned)e0 * DD + lane];
  }
  tables[(size_t)wid * DD + lane] = acc;
}

// ---------------- Kernel 4: gather output ------------------------------------
// Grid: 6144 blocks (XCD-swizzled). Wave per (h,n); lane = d. Full ILP batch:
// preload all 8 (w4,ip), issue all 32 table-row loads, fma in original order.
__global__ __launch_bounds__(256) void gather_out(
    const float* __restrict__ selw, const unsigned* __restrict__ selidx,
    const float* __restrict__ tables, float* __restrict__ out) {
  int wid = xcd_swz6144(blockIdx.x) * 4 + (threadIdx.x >> 6);
  int lane = threadIdx.x & 63;
  int h = wid >> 11;
  int n = wid & 2047;

  float4 w4[8]; unsigned ip[8];
#pragma unroll
  for (int t = 0; t < TT; ++t) {
    size_t o = ((size_t)NHT + (size_t)h * TT + t) * NN + n;   // side 1 (k)
    w4[t] = ((const float4*)selw)[o];
    ip[t] = selidx[o];
  }
  float f[32];
#pragma unroll
  for (int t = 0; t < TT; ++t) {
    const float* tb = tables + ((size_t)h * TT + t) * SS * DD;
    f[t*4+0] = tb[(ip[t] & 255u) * DD + lane];
    f[t*4+1] = tb[((ip[t] >> 8) & 255u) * DD + lane];
    f[t*4+2] = tb[((ip[t] >> 16) & 255u) * DD + lane];
    f[t*4+3] = tb[(ip[t] >> 24) * DD + lane];
  }
  float acc = 0.0f;
#pragma unroll
  for (int t = 0; t < TT; ++t) {
    acc += w4[t].x * f[t*4+0];
    acc += w4[t].y * f[t*4+1];
    acc += w4[t].z * f[t*4+2];
    acc += w4[t].w * f[t*4+3];
  }
  out[((size_t)h * NN + n) * DD + lane] = acc * 0.125f;
}

extern "C" void kernel_launch(void* const* d_in, const int* in_sizes, int n_in,
                              void* d_out, int out_size, void* d_ws, size_t ws_size,
                              hipStream_t stream) {
  const float* q    = (const float*)d_in[0];
  const float* k    = (const float*)d_in[1];
  const float* v    = (const float*)d_in[2];
  const float* mask = (const float*)d_in[3];
  const float* proj = (const float*)d_in[4];
  float* out = (float*)d_out;

  // ws: tables 6.29MB | selw 6.29MB | selidx 1.57MB | offsets 96KB |
  //     entries 6.29MB (~20.5MB; every element overwritten — no memset)
  float*    tables = (float*)d_ws;
  float*    selw   = tables + (size_t)NHT * SS * DD;
  unsigned* selidx = (unsigned*)(selw + (size_t)2 * NHT * NN * KK);
  unsigned* offsets = selidx + (size_t)2 * NHT * NN;
  unsigned long long* entries = (unsigned long long*)(offsets + (size_t)NHT * SS);

  select_topk<<<dim3(768), dim3(256), 0, stream>>>(q, k, proj, selw, selidx);
  scan_scatter<<<dim3(NHT), dim3(1024), 0, stream>>>(selw, selidx, mask, offsets, entries);
  build_tables<<<dim3(6144), dim3(256), 0, stream>>>(v, offsets, entries, tables);
  gather_out<<<dim3(6144), dim3(256), 0, stream>>>(selw, selidx, tables, out);
}